// Round 3
// baseline (320.334 us; speedup 1.0000x reference)
//
#include <hip/hip_runtime.h>

typedef unsigned short u16;
typedef __attribute__((ext_vector_type(8))) short bf16x8;
typedef __attribute__((ext_vector_type(4))) float f32x4;

__device__ __forceinline__ float bf2f(u16 u) { return __uint_as_float(((unsigned)u) << 16); }
__device__ __forceinline__ u16 f2bf(float f) {
  unsigned u = __float_as_uint(f);
  u += 0x7fffu + ((u >> 16) & 1u);   // RNE
  return (u16)(u >> 16);
}
__device__ __forceinline__ void bf2x2(unsigned w, float& lo, float& hi) {
  lo = __uint_as_float(w << 16);
  hi = __uint_as_float(w & 0xffff0000u);
}
__device__ __forceinline__ unsigned pk2(float lo, float hi) {
  return (unsigned)f2bf(lo) | ((unsigned)f2bf(hi) << 16);
}

// 8-lane group sum via ds_swizzle (xor 1,2,4 within 32-lane half).
__device__ __forceinline__ float red8(float p) {
  p += __int_as_float(__builtin_amdgcn_ds_swizzle(__float_as_int(p), 0x041F));
  p += __int_as_float(__builtin_amdgcn_ds_swizzle(__float_as_int(p), 0x081F));
  p += __int_as_float(__builtin_amdgcn_ds_swizzle(__float_as_int(p), 0x101F));
  return p;
}
// 4-lane group sum (aligned quads) via ds_swizzle xor 1,2.
__device__ __forceinline__ float red4(float p) {
  p += __int_as_float(__builtin_amdgcn_ds_swizzle(__float_as_int(p), 0x041F));
  p += __int_as_float(__builtin_amdgcn_ds_swizzle(__float_as_int(p), 0x081F));
  return p;
}

// ---------------------------------------------------------------------------
// Fused prep + weight pack (one dispatch):
// blocks [0, prepBlocks):  x->XH (hi bf16); BC1; BC2; zero cur[Nn].
// blocks [prepBlocks, +124): wtrans: transpose/split/pack weights (r13 layout)
// ---------------------------------------------------------------------------
__global__ __launch_bounds__(256) void prepw_kernel(
    const float* __restrict__ x,
    const float* __restrict__ bl1, const float* __restrict__ br1,
    const float* __restrict__ bl2, const float* __restrict__ br2,
    const float* __restrict__ Wl1, const float* __restrict__ Wr1,
    const float* __restrict__ Wl2, const float* __restrict__ Wr2,
    const float* __restrict__ Wjk,
    u16* __restrict__ XH, float* __restrict__ BC1, float* __restrict__ BC2,
    int* __restrict__ cur, u16* __restrict__ Wp,
    int nx, int total, int prepBlocks)
{
  if (blockIdx.x < prepBlocks) {
    int i = blockIdx.x * 256 + threadIdx.x;
    if (i >= total) return;
    if (i < nx) { XH[i] = f2bf(x[i]); return; }
    int j = i - nx;
    if (j < 1024) { BC1[j] = (j < 512) ? bl1[j] : br1[j - 512]; return; }
    if (j < 1536) { int t = j - 1024; BC2[t] = (t < 256) ? bl2[t] : br2[t - 256]; return; }
    cur[j - 1536] = 0;
    return;
  }
  // ---- wtrans body ----
  __shared__ float T[64][65];
  int t = blockIdx.x - prepBlocks;
  const float *Wa, *Wb; int Nhalf, lds, k0, n0, KsT, SUBS; size_t obase; bool split;
  if (t < 32) {
    int kt = t & 1, nt = t >> 1;
    k0 = kt * 64; n0 = nt * 64; obase = 0; KsT = 4; SUBS = 8; split = true;
    Wa = Wl1; Wb = Wr1; Nhalf = 512; lds = 512;
  } else if (t < 96) {
    int tt = t - 32; int kt = tt & 7, nt = tt >> 3;
    k0 = kt * 64; n0 = nt * 64; obase = 262144; KsT = 16; SUBS = 8; split = true;
    Wa = Wl2; Wb = Wr2; Nhalf = 256; lds = 256;
  } else {
    int tt = t - 96; int kt = tt % 14, nt = tt / 14;
    k0 = kt * 64; n0 = nt * 64; obase = 786432; KsT = 28; SUBS = 4; split = false;
    Wa = Wjk; Wb = nullptr; Nhalf = 128; lds = 128;
  }
  const int tid = threadIdx.x;
  const int lane = tid & 63, unit = tid >> 6;
  {
    int n = n0 + lane;
    const float* S = (n < Nhalf) ? Wa : Wb;
    int nn = (n < Nhalf) ? n : n - Nhalf;
#pragma unroll
    for (int r = 0; r < 16; ++r) {
      int kl = unit + 4 * r;
      T[kl][lane] = S[(size_t)(k0 + kl) * lds + nn];
    }
  }
  __syncthreads();
  const int tn = n0 >> 6;
#pragma unroll
  for (int u = 0; u < 2; ++u) {
    int c = unit * 2 + u;
    int ks_l = c >> 2, nc = c & 3;
    int ksg = (k0 >> 5) + ks_l;
    size_t ob = obase + ((size_t)(tn * KsT + ksg) * SUBS + nc) * 512 + lane * 8;
#pragma unroll
    for (int j = 0; j < 8; ++j) {
      float v = T[ks_l * 32 + (lane >> 4) * 8 + j][nc * 16 + (lane & 15)];
      u16 h = f2bf(v);
      Wp[ob + j] = h;
      if (split) Wp[ob + 2048 + j] = f2bf(v - bf2f(h));
    }
  }
}

// ---------------------------------------------------------------------------
// CSR build: histogram -> exclusive scan (shuffle) -> scatter srcs by dst
// ---------------------------------------------------------------------------
__global__ __launch_bounds__(256) void hist_kernel(
    const int* __restrict__ ei, int E, int ET, int* __restrict__ cnt)
{
  int e = blockIdx.x * 256 + threadIdx.x;
  if (e >= ET) return;
  int d = (e < E) ? ei[E + e] : (e - E);
  atomicAdd(&cnt[d], 1);
}

// scan also re-zeroes cnt (==cur) in place.
__global__ __launch_bounds__(1024) void scan_kernel(
    int* __restrict__ cnt, int* __restrict__ rowptr, int n)
{
  __shared__ int wsum[16];
  __shared__ int carry;
  const int tid = threadIdx.x, lane = tid & 63, wv = tid >> 6;
  if (tid == 0) carry = 0;
  __syncthreads();
  for (int base = 0; base < n; base += 1024) {
    int i = base + tid;
    int v = (i < n) ? cnt[i] : 0;
    if (i < n) cnt[i] = 0;
    int s = v;
#pragma unroll
    for (int ofs = 1; ofs < 64; ofs <<= 1) {
      int t = __shfl_up(s, ofs);
      if (lane >= ofs) s += t;
    }
    if (lane == 63) wsum[wv] = s;
    __syncthreads();
    if (wv == 0 && lane < 16) {
      int t = wsum[lane];
#pragma unroll
      for (int ofs = 1; ofs < 16; ofs <<= 1) {
        int u = __shfl_up(t, ofs);
        if (lane >= ofs) t += u;
      }
      wsum[lane] = t;
    }
    __syncthreads();
    int waveoff = (wv == 0) ? 0 : wsum[wv - 1];
    if (i < n) rowptr[i] = carry + waveoff + s - v;
    int tot = wsum[15];
    __syncthreads();
    if (tid == 0) carry += tot;
    __syncthreads();
  }
  if (threadIdx.x == 0) rowptr[n] = carry;
}

__global__ __launch_bounds__(256) void scatter_kernel(
    const int* __restrict__ ei, int E, int ET,
    const int* __restrict__ rowptr, int* __restrict__ cur, int* __restrict__ srcs)
{
  int e = blockIdx.x * 256 + threadIdx.x;
  if (e >= ET) return;
  int s, d;
  if (e < E) { s = ei[e]; d = ei[E + e]; } else { s = e - E; d = s; }
  int pos = rowptr[d] + atomicAdd(&cur[d], 1);
  srcs[pos] = s;
}

// ---------------------------------------------------------------------------
// GEMM v10 "gemmct" (operand-swap, packed weights) — unchanged from r13.
// ---------------------------------------------------------------------------
template<int MROWS, int NW, int WPE, bool SPLIT, bool BF16OUT, int LDSU16>
__global__ __launch_bounds__(NW * 64, WPE) void gemmct_kernel(
    const u16* __restrict__ A0, int lda0, int K0,
    const u16* __restrict__ A1, int lda1, int K1,
    const u16* __restrict__ A2, int lda2, int K2,
    const u16* __restrict__ Wp, int KsT,
    int kof0, int kof1, int kof2,
    const float* __restrict__ bias,
    void* __restrict__ Cv, int ldc, int M, int N)
{
  constexpr int SUBS = SPLIT ? 8 : 4;
  __shared__ u16 ldsA[LDSU16];
  const int tid  = threadIdx.x;
  const int lane = tid & 63;
  const int wv   = tid >> 6;
  const int quad = lane >> 4;
  const int r16  = lane & 15;
  const int m0   = blockIdx.x * MROWS;

  const u16* As[3]   = {A0, A1, A2};
  const int  Ks[3]   = {K0, K1, K2};
  const int  ldas[3] = {lda0, lda1, lda2};
  const int  kofs[3] = {kof0, kof1, kof2};

  int soff[3];
  int so = 0;
#pragma unroll
  for (int s = 0; s < 3; ++s) {
    const int K = Ks[s];
    soff[s] = so;
    if (K == 0) continue;
    const int stride = K + 8;
    const int cpr = K >> 3;
    const int sh  = 32 - __clz(cpr - 1);
    const int tot = MROWS << sh;
    for (int c = tid; c < tot; c += NW * 64) {
      int row = c >> sh, kc = c & ((1 << sh) - 1);
      if (kc < cpr) {
        int sr = m0 + row; if (sr >= M) sr = M - 1;
        uint4 v = *reinterpret_cast<const uint4*>(As[s] + (size_t)sr * ldas[s] + kc * 8);
        *reinterpret_cast<uint4*>(&ldsA[so + row * stride + kc * 8]) = v;
      }
    }
    so += MROWS * stride;
  }
  __syncthreads();

  constexpr int MM = MROWS / 16;
  for (int n0w = wv * 64; n0w < N; n0w += NW * 64) {
    const int t = n0w >> 6;
    f32x4 acc[MM][4];
#pragma unroll
    for (int mm = 0; mm < MM; ++mm)
#pragma unroll
      for (int nc = 0; nc < 4; ++nc) acc[mm][nc] = (f32x4){0.f, 0.f, 0.f, 0.f};

#pragma unroll
    for (int s = 0; s < 3; ++s) {
      const int K = Ks[s];
      if (K == 0) continue;
      const int stride = K + 8;
      const int ksb = kofs[s] >> 5;
      const u16* lbase = &ldsA[soff[s] + r16 * stride + quad * 8];

#pragma unroll 2
      for (int k0 = 0; k0 < K; k0 += 32) {
        const int ks = ksb + (k0 >> 5);
        const u16* ch = Wp + (((size_t)(t * KsT + ks) * SUBS) << 9) + lane * 8;
        bf16x8 af[MM];
#pragma unroll
        for (int mm = 0; mm < MM; ++mm)
          af[mm] = *reinterpret_cast<const bf16x8*>(lbase + mm * 16 * stride + k0);
        bf16x8 whf[4], wlf[4];
#pragma unroll
        for (int nc = 0; nc < 4; ++nc) {
          whf[nc] = *reinterpret_cast<const bf16x8*>(ch + (nc << 9));
          if (SPLIT) wlf[nc] = *reinterpret_cast<const bf16x8*>(ch + ((4 + nc) << 9));
        }
#pragma unroll
        for (int mm = 0; mm < MM; ++mm)
#pragma unroll
          for (int nc = 0; nc < 4; ++nc) {
            acc[mm][nc] = __builtin_amdgcn_mfma_f32_16x16x32_bf16(whf[nc], af[mm], acc[mm][nc], 0, 0, 0);
            if (SPLIT)
              acc[mm][nc] = __builtin_amdgcn_mfma_f32_16x16x32_bf16(wlf[nc], af[mm], acc[mm][nc], 0, 0, 0);
          }
      }
    }

#pragma unroll
    for (int mm = 0; mm < MM; ++mm) {
      const int m = m0 + mm * 16 + r16;
      if (m >= M) continue;
#pragma unroll
      for (int nc = 0; nc < 4; ++nc) {
        const int n = n0w + nc * 16 + quad * 4;
        float b0 = 0.f, b1 = 0.f, b2 = 0.f, b3 = 0.f;
        if (bias) {
          float4 bv = *reinterpret_cast<const float4*>(bias + n);
          b0 = bv.x; b1 = bv.y; b2 = bv.z; b3 = bv.w;
        }
        float v0 = acc[mm][nc][0] + b0;
        float v1 = acc[mm][nc][1] + b1;
        float v2 = acc[mm][nc][2] + b2;
        float v3 = acc[mm][nc][3] + b3;
        if (BF16OUT) {
          ushort4 o = { f2bf(v0), f2bf(v1), f2bf(v2), f2bf(v3) };
          *reinterpret_cast<ushort4*>((u16*)Cv + (size_t)m * ldc + n) = o;
        } else {
          float4 o = { v0, v1, v2, v3 };
          *reinterpret_cast<float4*>((float*)Cv + (size_t)m * ldc + n) = o;
        }
      }
    }
  }
}

// ---------------------------------------------------------------------------
// Layer-1 GATv2 aggregation (D=512): one wave per dst node, 6-edge ILP.
// Full wave per edge (16B/lane). Packed uint4 output stores.
// ---------------------------------------------------------------------------
template<int VPL>
__device__ __forceinline__ void load_row(const u16* p, float* dst) {
  if constexpr (VPL == 8) {
    uint4 t = *reinterpret_cast<const uint4*>(p);
    bf2x2(t.x, dst[0], dst[1]); bf2x2(t.y, dst[2], dst[3]);
    bf2x2(t.z, dst[4], dst[5]); bf2x2(t.w, dst[6], dst[7]);
  } else {
    uint2 t = *reinterpret_cast<const uint2*>(p);
    bf2x2(t.x, dst[0], dst[1]); bf2x2(t.y, dst[2], dst[3]);
  }
}

__global__ __launch_bounds__(256) void gat_node1_kernel(
    const u16* __restrict__ XLR,
    const int* __restrict__ rowptr, const int* __restrict__ srcs,
    const float* __restrict__ att, const float* __restrict__ bias,
    u16* __restrict__ Hh, int Nn)
{
  constexpr int D = 512;
  constexpr int VPL = 8;
  const int lane = threadIdx.x & 63;
  const int wv  = (blockIdx.x * 256 + threadIdx.x) >> 6;
  const int nwv = (gridDim.x * 256) >> 6;

  float c1[VPL], c2[VPL], biasR[VPL];
#pragma unroll
  for (int w = 0; w < VPL; ++w) {
    float a = att[lane * VPL + w];
    c1[w] = 0.6f * a;
    c2[w] = 0.4f * a;
    biasR[w] = bias[lane * VPL + w];
  }

  for (int d = wv; d < Nn; d += nwv) {
    float xr[VPL];
    load_row<VPL>(XLR + (size_t)d * (2 * D) + D + lane * VPL, xr);

    const int jb = rowptr[d], je = rowptr[d + 1];

    float acc[VPL];
    load_row<VPL>(XLR + (size_t)srcs[jb] * (2 * D) + lane * VPL, acc);
    float p0 = 0.f;
#pragma unroll
    for (int w = 0; w < VPL; ++w) {
      float v = acc[w] + xr[w];
      p0 = fmaf(c1[w], v, fmaf(c2[w], fabsf(v), p0));
    }
    p0 = red8(p0);
    float den = 1.f;

    int j = jb + 1;
    for (; j + 5 < je; j += 6) {
      float xs[6][VPL];
      float p[6];
#pragma unroll
      for (int q = 0; q < 6; ++q)
        load_row<VPL>(XLR + (size_t)srcs[j + q] * (2 * D) + lane * VPL, xs[q]);
#pragma unroll
      for (int q = 0; q < 6; ++q) {
        float pp = 0.f;
#pragma unroll
        for (int w = 0; w < VPL; ++w) {
          float v = xs[q][w] + xr[w];
          pp = fmaf(c1[w], v, fmaf(c2[w], fabsf(v), pp));
        }
        p[q] = pp;
      }
#pragma unroll
      for (int q = 0; q < 6; ++q)
        p[q] += __int_as_float(__builtin_amdgcn_ds_swizzle(__float_as_int(p[q]), 0x041F));
#pragma unroll
      for (int q = 0; q < 6; ++q)
        p[q] += __int_as_float(__builtin_amdgcn_ds_swizzle(__float_as_int(p[q]), 0x081F));
#pragma unroll
      for (int q = 0; q < 6; ++q)
        p[q] += __int_as_float(__builtin_amdgcn_ds_swizzle(__float_as_int(p[q]), 0x101F));
      float e[6];
#pragma unroll
      for (int q = 0; q < 6; ++q) e[q] = __expf(p[q] - p0);
      den += ((e[0] + e[1]) + (e[2] + e[3])) + (e[4] + e[5]);
#pragma unroll
      for (int w = 0; w < VPL; ++w) {
        float t0 = fmaf(e[0], xs[0][w], fmaf(e[1], xs[1][w], acc[w]));
        float t1 = fmaf(e[2], xs[2][w], fmaf(e[3], xs[3][w], t0));
        acc[w] = fmaf(e[4], xs[4][w], fmaf(e[5], xs[5][w], t1));
      }
    }
    if (j + 3 < je) {
      float xs[4][VPL];
      float p[4];
#pragma unroll
      for (int q = 0; q < 4; ++q)
        load_row<VPL>(XLR + (size_t)srcs[j + q] * (2 * D) + lane * VPL, xs[q]);
#pragma unroll
      for (int q = 0; q < 4; ++q) {
        float pp = 0.f;
#pragma unroll
        for (int w = 0; w < VPL; ++w) {
          float v = xs[q][w] + xr[w];
          pp = fmaf(c1[w], v, fmaf(c2[w], fabsf(v), pp));
        }
        p[q] = pp;
      }
#pragma unroll
      for (int q = 0; q < 4; ++q)
        p[q] += __int_as_float(__builtin_amdgcn_ds_swizzle(__float_as_int(p[q]), 0x041F));
#pragma unroll
      for (int q = 0; q < 4; ++q)
        p[q] += __int_as_float(__builtin_amdgcn_ds_swizzle(__float_as_int(p[q]), 0x081F));
#pragma unroll
      for (int q = 0; q < 4; ++q)
        p[q] += __int_as_float(__builtin_amdgcn_ds_swizzle(__float_as_int(p[q]), 0x101F));
      float e[4];
#pragma unroll
      for (int q = 0; q < 4; ++q) e[q] = __expf(p[q] - p0);
      den += (e[0] + e[1]) + (e[2] + e[3]);
#pragma unroll
      for (int w = 0; w < VPL; ++w) {
        float t0 = fmaf(e[0], xs[0][w], fmaf(e[1], xs[1][w], acc[w]));
        acc[w] = fmaf(e[2], xs[2][w], fmaf(e[3], xs[3][w], t0));
      }
      j += 4;
    }
    if (j + 1 < je) {
      float xa[VPL], xb[VPL];
      load_row<VPL>(XLR + (size_t)srcs[j]     * (2 * D) + lane * VPL, xa);
      load_row<VPL>(XLR + (size_t)srcs[j + 1] * (2 * D) + lane * VPL, xb);
      float pa = 0.f, pb = 0.f;
#pragma unroll
      for (int w = 0; w < VPL; ++w) {
        float va = xa[w] + xr[w];
        float vb = xb[w] + xr[w];
        pa = fmaf(c1[w], va, fmaf(c2[w], fabsf(va), pa));
        pb = fmaf(c1[w], vb, fmaf(c2[w], fabsf(vb), pb));
      }
      pa = red8(pa); pb = red8(pb);
      const float ea = __expf(pa - p0);
      const float eb = __expf(pb - p0);
      den += ea + eb;
#pragma unroll
      for (int w = 0; w < VPL; ++w)
        acc[w] = fmaf(ea, xa[w], fmaf(eb, xb[w], acc[w]));
      j += 2;
    }
    if (j < je) {
      float xa[VPL];
      load_row<VPL>(XLR + (size_t)srcs[j] * (2 * D) + lane * VPL, xa);
      float pa = 0.f;
#pragma unroll
      for (int w = 0; w < VPL; ++w) {
        float va = xa[w] + xr[w];
        pa = fmaf(c1[w], va, fmaf(c2[w], fabsf(va), pa));
      }
      pa = red8(pa);
      const float ea = __expf(pa - p0);
      den += ea;
#pragma unroll
      for (int w = 0; w < VPL; ++w) acc[w] = fmaf(ea, xa[w], acc[w]);
    }

    const float inv = 1.f / den;
    float o[VPL];
#pragma unroll
    for (int w = 0; w < VPL; ++w) {
      float v = fmaf(acc[w], inv, biasR[w]);
      o[w] = v > 0.f ? v : (__expf(v) - 1.f);
    }
    uint4 ov = { pk2(o[0], o[1]), pk2(o[2], o[3]), pk2(o[4], o[5]), pk2(o[6], o[7]) };
    *reinterpret_cast<uint4*>(Hh + (size_t)d * D + lane * VPL) = ov;
  }
}

// ---------------------------------------------------------------------------
// Layer-2 GATv2 aggregation (D=256): HALF-WAVE per edge — lanes 0-31 process
// edge j, lanes 32-63 edge j+1, each half covering the full 256-dim row at
// 16B/lane. One dwordx4 wave-load covers TWO edges (halves the VMEM
// instruction count vs 8B/lane full-wave). Head (32 dims) = aligned 4-lane
// group -> red4. Halves merge once per node via __shfl_xor(.,32).
// ---------------------------------------------------------------------------
__global__ __launch_bounds__(256) void gat_node2_kernel(
    const u16* __restrict__ XLR,
    const int* __restrict__ rowptr, const int* __restrict__ srcs,
    const float* __restrict__ att, const float* __restrict__ bias,
    u16* __restrict__ Hh, int Nn)
{
  constexpr int D = 256;
  const int lane = threadIdx.x & 63;
  const int half = lane >> 5;
  const int l32  = lane & 31;
  const int wv  = (blockIdx.x * 256 + threadIdx.x) >> 6;
  const int nwv = (gridDim.x * 256) >> 6;

  float c1[8], c2[8], biasR[8];
#pragma unroll
  for (int w = 0; w < 8; ++w) {
    float a = att[l32 * 8 + w];
    c1[w] = 0.6f * a;
    c2[w] = 0.4f * a;
    biasR[w] = bias[l32 * 8 + w];
  }

  for (int d = wv; d < Nn; d += nwv) {
    float xr[8];
    load_row<8>(XLR + (size_t)d * (2 * D) + D + l32 * 8, xr);

    const int jb = rowptr[d], je = rowptr[d + 1];

    // reference edge loaded by BOTH halves (identical p0); only the lower
    // half keeps its contribution (acc, den) to avoid double counting.
    float acc[8];
    load_row<8>(XLR + (size_t)srcs[jb] * (2 * D) + l32 * 8, acc);
    float p0 = 0.f;
#pragma unroll
    for (int w = 0; w < 8; ++w) {
      float v = acc[w] + xr[w];
      p0 = fmaf(c1[w], v, fmaf(c2[w], fabsf(v), p0));
    }
    p0 = red4(p0);
    float den;
    if (half) {
      den = 0.f;
#pragma unroll
      for (int w = 0; w < 8; ++w) acc[w] = 0.f;
    } else {
      den = 1.f;
    }

    int j = jb + 1;
    // ---- main loop: 4 load-instructions cover 8 edges ----
    for (; j + 7 < je; j += 8) {
      float xs[4][8];
      float p[4];
#pragma unroll
      for (int q = 0; q < 4; ++q)
        load_row<8>(XLR + (size_t)srcs[j + 2 * q + half] * (2 * D) + l32 * 8, xs[q]);
#pragma unroll
      for (int q = 0; q < 4; ++q) {
        float pp = 0.f;
#pragma unroll
        for (int w = 0; w < 8; ++w) {
          float v = xs[q][w] + xr[w];
          pp = fmaf(c1[w], v, fmaf(c2[w], fabsf(v), pp));
        }
        p[q] = pp;
      }
#pragma unroll
      for (int q = 0; q < 4; ++q)
        p[q] += __int_as_float(__builtin_amdgcn_ds_swizzle(__float_as_int(p[q]), 0x041F));
#pragma unroll
      for (int q = 0; q < 4; ++q)
        p[q] += __int_as_float(__builtin_amdgcn_ds_swizzle(__float_as_int(p[q]), 0x081F));
      float e[4];
#pragma unroll
      for (int q = 0; q < 4; ++q) e[q] = __expf(p[q] - p0);
      den += (e[0] + e[1]) + (e[2] + e[3]);
#pragma unroll
      for (int w = 0; w < 8; ++w) {
        float t0 = fmaf(e[0], xs[0][w], fmaf(e[1], xs[1][w], acc[w]));
        acc[w] = fmaf(e[2], xs[2][w], fmaf(e[3], xs[3][w], t0));
      }
    }
    // ---- tail: one pair (2 edges) per iteration, masked ----
    for (; j < je; j += 2) {
      int jj = j + half;
      const bool valid = jj < je;
      if (!valid) jj = je - 1;
      float xa[8];
      load_row<8>(XLR + (size_t)srcs[jj] * (2 * D) + l32 * 8, xa);
      float pa = 0.f;
#pragma unroll
      for (int w = 0; w < 8; ++w) {
        float v = xa[w] + xr[w];
        pa = fmaf(c1[w], v, fmaf(c2[w], fabsf(v), pa));
      }
      pa = red4(pa);
      const float ea = valid ? __expf(pa - p0) : 0.f;
      den += ea;
#pragma unroll
      for (int w = 0; w < 8; ++w) acc[w] = fmaf(ea, xa[w], acc[w]);
    }

    // ---- merge halves ----
    den += __shfl_xor(den, 32);
#pragma unroll
    for (int w = 0; w < 8; ++w) acc[w] += __shfl_xor(acc[w], 32);

    if (half == 0) {
      const float inv = 1.f / den;
      float o[8];
#pragma unroll
      for (int w = 0; w < 8; ++w) {
        float v = fmaf(acc[w], inv, biasR[w]);
        o[w] = v > 0.f ? v : (__expf(v) - 1.f);
      }
      uint4 ov = { pk2(o[0], o[1]), pk2(o[2], o[3]), pk2(o[4], o[5]), pk2(o[6], o[7]) };
      *reinterpret_cast<uint4*>(Hh + (size_t)d * D + l32 * 8) = ov;
    }
  }
}

// ---------------------------------------------------------------------------

extern "C" void kernel_launch(void* const* d_in, const int* in_sizes, int n_in,
                              void* d_out, int out_size, void* d_ws, size_t ws_size,
                              hipStream_t stream) {
  const float* x     = (const float*)d_in[0];
  const int*   ei    = (const int*)d_in[1];
  const float* Wl1   = (const float*)d_in[2];
  const float* bl1   = (const float*)d_in[3];
  const float* Wr1   = (const float*)d_in[4];
  const float* br1   = (const float*)d_in[5];
  const float* att1  = (const float*)d_in[6];
  const float* bias1 = (const float*)d_in[7];
  const float* Wl2   = (const float*)d_in[8];
  const float* bl2   = (const float*)d_in[9];
  const float* Wr2   = (const float*)d_in[10];
  const float* br2   = (const float*)d_in[11];
  const float* att2  = (const float*)d_in[12];
  const float* bias2 = (const float*)d_in[13];
  const float* Wjk   = (const float*)d_in[14];
  const float* bjk   = (const float*)d_in[15];
  float* out = (float*)d_out;

  const int Nn = in_sizes[0] / 128;   // 20000
  const int E  = in_sizes[1] / 2;     // 320000
  const int ET = E + Nn;              // 340000

  const size_t nx = (size_t)Nn * 128;

  // packed weight region bases (u16 elements)
  const size_t oW1  = 0;
  const size_t oW2  = 262144;
  const size_t oWjk = 786432;
  const size_t npack = 901120;

  // workspace (~85 MB)
  char* ws = (char*)d_ws;
  size_t off = 0;
  u16* XH = (u16*)(ws + off); off += nx * 2;
  u16* Wp = (u16*)(ws + off); off += npack * 2;
  float* BC1 = (float*)(ws + off); off += 1024 * 4;
  float* BC2 = (float*)(ws + off); off += 512 * 4;
  u16* XLR1 = (u16*)(ws + off);               // [N][1024] bf16
  u16* XLR2 = XLR1;                           // [N][512]  (sequential reuse)
  off += (size_t)Nn * 1024 * 2;
  u16* H1h = (u16*)(ws + off); off += (size_t)Nn * 512 * 2;
  u16* H2h = (u16*)(ws + off); off += (size_t)Nn * 256 * 2;
  int* rowptr = (int*)(ws + off); off += (size_t)(Nn + 1) * 4;
  int* cur    = (int*)(ws + off); off += (size_t)Nn * 4;
  int* srcs   = (int*)(ws + off); off += (size_t)ET * 4;

  const int nodeblocks = 5000;   // 20000 waves: 1 node/wave, CP load-balanced

  // ---------------- fused prep+wtrans + CSR build ----------------
  const int nprep = (int)(nx + 1536 + Nn);
  const int prepBlocks = (nprep + 255) / 256;
  prepw_kernel<<<prepBlocks + 124, 256, 0, stream>>>(
      x, bl1, br1, bl2, br2, Wl1, Wr1, Wl2, Wr2, Wjk,
      XH, BC1, BC2, cur, Wp, (int)nx, nprep, prepBlocks);
  hist_kernel<<<(ET + 255) / 256, 256, 0, stream>>>(ei, E, ET, cur);
  scan_kernel<<<1, 1024, 0, stream>>>(cur, rowptr, Nn);   // also re-zeroes cur
  scatter_kernel<<<(ET + 255) / 256, 256, 0, stream>>>(ei, E, ET, rowptr, cur, srcs);

  // ---------------- Layer 1: XLR1 = XH @ [Wl1|Wr1] (2-term split) ----------
  gemmct_kernel<32, 8, 4, true, true, 32 * 136>
      <<<(Nn + 31) / 32, 512, 0, stream>>>(
      XH, 128, 128, nullptr, 0, 0, nullptr, 0, 0,
      Wp + oW1, 4, 0, 0, 0, BC1,
      XLR1, 1024, Nn, 1024);
  gat_node1_kernel<<<nodeblocks, 256, 0, stream>>>(
      XLR1, rowptr, srcs, att1, bias1, H1h, Nn);

  // ---------------- Layer 2: XLR2 = H1h @ [Wl2|Wr2] (2-term split) ---------
  gemmct_kernel<48, 8, 4, true, true, 48 * 520>
      <<<(Nn + 47) / 48, 512, 0, stream>>>(
      H1h, 512, 512, nullptr, 0, 0, nullptr, 0, 0,
      Wp + oW2, 16, 0, 0, 0, BC2,
      XLR2, 512, Nn, 512);
  gat_node2_kernel<<<nodeblocks, 256, 0, stream>>>(
      XLR2, rowptr, srcs, att2, bias2, H2h, Nn);

  // ---------------- JK: out = [x|h1|h2] @ Wjk + bjk (hi-only, f32 out) -----
  gemmct_kernel<16, 2, 1, false, false, 16 * 920>
      <<<(Nn + 15) / 16, 128, 0, stream>>>(
      XH, 128, 128, H1h, 512, 512, H2h, 256, 256,
      Wp + oWjk, 28, 0, 128, 640, bjk,
      out, 128, Nn, 128);
}

// Round 4
// 307.982 us; speedup vs baseline: 1.0401x; 1.0401x over previous
//
#include <hip/hip_runtime.h>

typedef unsigned short u16;
typedef __attribute__((ext_vector_type(8))) short bf16x8;
typedef __attribute__((ext_vector_type(4))) float f32x4;

__device__ __forceinline__ float bf2f(u16 u) { return __uint_as_float(((unsigned)u) << 16); }
__device__ __forceinline__ u16 f2bf(float f) {
  unsigned u = __float_as_uint(f);
  u += 0x7fffu + ((u >> 16) & 1u);   // RNE
  return (u16)(u >> 16);
}
__device__ __forceinline__ void bf2x2(unsigned w, float& lo, float& hi) {
  lo = __uint_as_float(w << 16);
  hi = __uint_as_float(w & 0xffff0000u);
}
__device__ __forceinline__ unsigned pk2(float lo, float hi) {
  return (unsigned)f2bf(lo) | ((unsigned)f2bf(hi) << 16);
}

// ---------------------------------------------------------------------------
// Fused prep + weight pack (one dispatch):
// blocks [0, prepBlocks):  x->XH (hi bf16); BC1; BC2; zero cur[Nn].
// blocks [prepBlocks, +124): wtrans: transpose/split/pack weights (r13 layout)
// ---------------------------------------------------------------------------
__global__ __launch_bounds__(256) void prepw_kernel(
    const float* __restrict__ x,
    const float* __restrict__ bl1, const float* __restrict__ br1,
    const float* __restrict__ bl2, const float* __restrict__ br2,
    const float* __restrict__ Wl1, const float* __restrict__ Wr1,
    const float* __restrict__ Wl2, const float* __restrict__ Wr2,
    const float* __restrict__ Wjk,
    u16* __restrict__ XH, float* __restrict__ BC1, float* __restrict__ BC2,
    int* __restrict__ cur, u16* __restrict__ Wp,
    int nx, int total, int prepBlocks)
{
  if (blockIdx.x < prepBlocks) {
    int i = blockIdx.x * 256 + threadIdx.x;
    if (i >= total) return;
    if (i < nx) { XH[i] = f2bf(x[i]); return; }
    int j = i - nx;
    if (j < 1024) { BC1[j] = (j < 512) ? bl1[j] : br1[j - 512]; return; }
    if (j < 1536) { int t = j - 1024; BC2[t] = (t < 256) ? bl2[t] : br2[t - 256]; return; }
    cur[j - 1536] = 0;
    return;
  }
  // ---- wtrans body ----
  __shared__ float T[64][65];
  int t = blockIdx.x - prepBlocks;
  const float *Wa, *Wb; int Nhalf, lds, k0, n0, KsT, SUBS; size_t obase; bool split;
  if (t < 32) {
    int kt = t & 1, nt = t >> 1;
    k0 = kt * 64; n0 = nt * 64; obase = 0; KsT = 4; SUBS = 8; split = true;
    Wa = Wl1; Wb = Wr1; Nhalf = 512; lds = 512;
  } else if (t < 96) {
    int tt = t - 32; int kt = tt & 7, nt = tt >> 3;
    k0 = kt * 64; n0 = nt * 64; obase = 262144; KsT = 16; SUBS = 8; split = true;
    Wa = Wl2; Wb = Wr2; Nhalf = 256; lds = 256;
  } else {
    int tt = t - 96; int kt = tt % 14, nt = tt / 14;
    k0 = kt * 64; n0 = nt * 64; obase = 786432; KsT = 28; SUBS = 4; split = false;
    Wa = Wjk; Wb = nullptr; Nhalf = 128; lds = 128;
  }
  const int tid = threadIdx.x;
  const int lane = tid & 63, unit = tid >> 6;
  {
    int n = n0 + lane;
    const float* S = (n < Nhalf) ? Wa : Wb;
    int nn = (n < Nhalf) ? n : n - Nhalf;
#pragma unroll
    for (int r = 0; r < 16; ++r) {
      int kl = unit + 4 * r;
      T[kl][lane] = S[(size_t)(k0 + kl) * lds + nn];
    }
  }
  __syncthreads();
  const int tn = n0 >> 6;
#pragma unroll
  for (int u = 0; u < 2; ++u) {
    int c = unit * 2 + u;
    int ks_l = c >> 2, nc = c & 3;
    int ksg = (k0 >> 5) + ks_l;
    size_t ob = obase + ((size_t)(tn * KsT + ksg) * SUBS + nc) * 512 + lane * 8;
#pragma unroll
    for (int j = 0; j < 8; ++j) {
      float v = T[ks_l * 32 + (lane >> 4) * 8 + j][nc * 16 + (lane & 15)];
      u16 h = f2bf(v);
      Wp[ob + j] = h;
      if (split) Wp[ob + 2048 + j] = f2bf(v - bf2f(h));
    }
  }
}

// ---------------------------------------------------------------------------
// CSR build: histogram -> exclusive scan (shuffle) -> scatter srcs by dst
// ---------------------------------------------------------------------------
__global__ __launch_bounds__(256) void hist_kernel(
    const int* __restrict__ ei, int E, int ET, int* __restrict__ cnt)
{
  int e = blockIdx.x * 256 + threadIdx.x;
  if (e >= ET) return;
  int d = (e < E) ? ei[E + e] : (e - E);
  atomicAdd(&cnt[d], 1);
}

// scan also re-zeroes cnt (==cur) in place.
__global__ __launch_bounds__(1024) void scan_kernel(
    int* __restrict__ cnt, int* __restrict__ rowptr, int n)
{
  __shared__ int wsum[16];
  __shared__ int carry;
  const int tid = threadIdx.x, lane = tid & 63, wv = tid >> 6;
  if (tid == 0) carry = 0;
  __syncthreads();
  for (int base = 0; base < n; base += 1024) {
    int i = base + tid;
    int v = (i < n) ? cnt[i] : 0;
    if (i < n) cnt[i] = 0;
    int s = v;
#pragma unroll
    for (int ofs = 1; ofs < 64; ofs <<= 1) {
      int t = __shfl_up(s, ofs);
      if (lane >= ofs) s += t;
    }
    if (lane == 63) wsum[wv] = s;
    __syncthreads();
    if (wv == 0 && lane < 16) {
      int t = wsum[lane];
#pragma unroll
      for (int ofs = 1; ofs < 16; ofs <<= 1) {
        int u = __shfl_up(t, ofs);
        if (lane >= ofs) t += u;
      }
      wsum[lane] = t;
    }
    __syncthreads();
    int waveoff = (wv == 0) ? 0 : wsum[wv - 1];
    if (i < n) rowptr[i] = carry + waveoff + s - v;
    int tot = wsum[15];
    __syncthreads();
    if (tid == 0) carry += tot;
    __syncthreads();
  }
  if (threadIdx.x == 0) rowptr[n] = carry;
}

// ---------------------------------------------------------------------------
// GEMM v10 "gemmct" body (operand-swap, packed weights) — device function so
// it can be fused with independent work (scatter) in one dispatch.
// ---------------------------------------------------------------------------
template<int MROWS, int NW, bool SPLIT, bool BF16OUT>
__device__ __forceinline__ void gemmct_body(
    u16* __restrict__ ldsA, int bid,
    const u16* __restrict__ A0, int lda0, int K0,
    const u16* __restrict__ A1, int lda1, int K1,
    const u16* __restrict__ A2, int lda2, int K2,
    const u16* __restrict__ Wp, int KsT,
    int kof0, int kof1, int kof2,
    const float* __restrict__ bias,
    void* __restrict__ Cv, int ldc, int M, int N)
{
  constexpr int SUBS = SPLIT ? 8 : 4;
  const int tid  = threadIdx.x;
  const int lane = tid & 63;
  const int wv   = tid >> 6;
  const int quad = lane >> 4;
  const int r16  = lane & 15;
  const int m0   = bid * MROWS;

  const u16* As[3]   = {A0, A1, A2};
  const int  Ks[3]   = {K0, K1, K2};
  const int  ldas[3] = {lda0, lda1, lda2};
  const int  kofs[3] = {kof0, kof1, kof2};

  int soff[3];
  int so = 0;
#pragma unroll
  for (int s = 0; s < 3; ++s) {
    const int K = Ks[s];
    soff[s] = so;
    if (K == 0) continue;
    const int stride = K + 8;
    const int cpr = K >> 3;
    const int sh  = 32 - __clz(cpr - 1);
    const int tot = MROWS << sh;
    for (int c = tid; c < tot; c += NW * 64) {
      int row = c >> sh, kc = c & ((1 << sh) - 1);
      if (kc < cpr) {
        int sr = m0 + row; if (sr >= M) sr = M - 1;
        uint4 v = *reinterpret_cast<const uint4*>(As[s] + (size_t)sr * ldas[s] + kc * 8);
        *reinterpret_cast<uint4*>(&ldsA[so + row * stride + kc * 8]) = v;
      }
    }
    so += MROWS * stride;
  }
  __syncthreads();

  constexpr int MM = MROWS / 16;
  for (int n0w = wv * 64; n0w < N; n0w += NW * 64) {
    const int t = n0w >> 6;
    f32x4 acc[MM][4];
#pragma unroll
    for (int mm = 0; mm < MM; ++mm)
#pragma unroll
      for (int nc = 0; nc < 4; ++nc) acc[mm][nc] = (f32x4){0.f, 0.f, 0.f, 0.f};

#pragma unroll
    for (int s = 0; s < 3; ++s) {
      const int K = Ks[s];
      if (K == 0) continue;
      const int stride = K + 8;
      const int ksb = kofs[s] >> 5;
      const u16* lbase = &ldsA[soff[s] + r16 * stride + quad * 8];

#pragma unroll 2
      for (int k0 = 0; k0 < K; k0 += 32) {
        const int ks = ksb + (k0 >> 5);
        const u16* ch = Wp + (((size_t)(t * KsT + ks) * SUBS) << 9) + lane * 8;
        bf16x8 af[MM];
#pragma unroll
        for (int mm = 0; mm < MM; ++mm)
          af[mm] = *reinterpret_cast<const bf16x8*>(lbase + mm * 16 * stride + k0);
        bf16x8 whf[4], wlf[4];
#pragma unroll
        for (int nc = 0; nc < 4; ++nc) {
          whf[nc] = *reinterpret_cast<const bf16x8*>(ch + (nc << 9));
          if (SPLIT) wlf[nc] = *reinterpret_cast<const bf16x8*>(ch + ((4 + nc) << 9));
        }
#pragma unroll
        for (int mm = 0; mm < MM; ++mm)
#pragma unroll
          for (int nc = 0; nc < 4; ++nc) {
            acc[mm][nc] = __builtin_amdgcn_mfma_f32_16x16x32_bf16(whf[nc], af[mm], acc[mm][nc], 0, 0, 0);
            if (SPLIT)
              acc[mm][nc] = __builtin_amdgcn_mfma_f32_16x16x32_bf16(wlf[nc], af[mm], acc[mm][nc], 0, 0, 0);
          }
      }
    }

#pragma unroll
    for (int mm = 0; mm < MM; ++mm) {
      const int m = m0 + mm * 16 + r16;
      if (m >= M) continue;
#pragma unroll
      for (int nc = 0; nc < 4; ++nc) {
        const int n = n0w + nc * 16 + quad * 4;
        float b0 = 0.f, b1 = 0.f, b2 = 0.f, b3 = 0.f;
        if (bias) {
          float4 bv = *reinterpret_cast<const float4*>(bias + n);
          b0 = bv.x; b1 = bv.y; b2 = bv.z; b3 = bv.w;
        }
        float v0 = acc[mm][nc][0] + b0;
        float v1 = acc[mm][nc][1] + b1;
        float v2 = acc[mm][nc][2] + b2;
        float v3 = acc[mm][nc][3] + b3;
        if (BF16OUT) {
          ushort4 o = { f2bf(v0), f2bf(v1), f2bf(v2), f2bf(v3) };
          *reinterpret_cast<ushort4*>((u16*)Cv + (size_t)m * ldc + n) = o;
        } else {
          float4 o = { v0, v1, v2, v3 };
          *reinterpret_cast<float4*>((float*)Cv + (size_t)m * ldc + n) = o;
        }
      }
    }
  }
}

template<int MROWS, int NW, int WPE, bool SPLIT, bool BF16OUT, int LDSU16>
__global__ __launch_bounds__(NW * 64, WPE) void gemmct_kernel(
    const u16* __restrict__ A0, int lda0, int K0,
    const u16* __restrict__ A1, int lda1, int K1,
    const u16* __restrict__ A2, int lda2, int K2,
    const u16* __restrict__ Wp, int KsT,
    int kof0, int kof1, int kof2,
    const float* __restrict__ bias,
    void* __restrict__ Cv, int ldc, int M, int N)
{
  __shared__ u16 ldsA[LDSU16];
  gemmct_body<MROWS, NW, SPLIT, BF16OUT>(
      ldsA, blockIdx.x, A0, lda0, K0, A1, lda1, K1, A2, lda2, K2,
      Wp, KsT, kof0, kof1, kof2, bias, Cv, ldc, M, N);
}

// gemm1 + scatter fused: blocks [0,gemmBlocks) run gemm1; the rest scatter
// srcs by dst (both only depend on scan's output / prepw's output).
template<int MROWS, int NW, int WPE, bool SPLIT, bool BF16OUT, int LDSU16>
__global__ __launch_bounds__(NW * 64, WPE) void gemm1_scatter_kernel(
    const u16* __restrict__ A0, int lda0, int K0,
    const u16* __restrict__ Wp, int KsT,
    const float* __restrict__ bias,
    void* __restrict__ Cv, int ldc, int M, int N, int gemmBlocks,
    const int* __restrict__ ei, int E, int ET,
    const int* __restrict__ rowptr, int* __restrict__ cur, int* __restrict__ srcs)
{
  __shared__ u16 ldsA[LDSU16];
  if ((int)blockIdx.x < gemmBlocks) {
    gemmct_body<MROWS, NW, SPLIT, BF16OUT>(
        ldsA, blockIdx.x, A0, lda0, K0, nullptr, 0, 0, nullptr, 0, 0,
        Wp, KsT, 0, 0, 0, bias, Cv, ldc, M, N);
    return;
  }
  int e = ((int)blockIdx.x - gemmBlocks) * (NW * 64) + (int)threadIdx.x;
  if (e >= ET) return;
  int s, d;
  if (e < E) { s = ei[e]; d = ei[E + e]; } else { s = e - E; d = s; }
  int pos = rowptr[d] + atomicAdd(&cur[d], 1);
  srcs[pos] = s;
}

// ---------------------------------------------------------------------------
// GATv2 aggregation, software-pipelined gathers.
// One wave per dst node. Groups of 6 edges (gat1, full-wave 16B/lane) or
// 8 edges (gat2, half-wave split). The NEXT group's row-gathers are issued
// BEFORE the current group's dot/swizzle/exp phase, so ~6 KB of loads stay in
// flight per wave during compute (ping-pong register groups xs/ys, no copies;
// vmcnt waits land at first use = next compute). Group consumption order and
// accumulation order identical to the non-pipelined version (bit-identical).
// lrelu folded: lrelu(v)*att = (0.6att)v + (0.4att)|v|.
// XLR row (u16): [xl(0..D-1) | xr(D..2D-1)].
// ---------------------------------------------------------------------------
template<int VPL>
__device__ __forceinline__ void load_row(const u16* p, float* dst) {
  if constexpr (VPL == 8) {
    uint4 t = *reinterpret_cast<const uint4*>(p);
    bf2x2(t.x, dst[0], dst[1]); bf2x2(t.y, dst[2], dst[3]);
    bf2x2(t.z, dst[4], dst[5]); bf2x2(t.w, dst[6], dst[7]);
  } else {
    uint2 t = *reinterpret_cast<const uint2*>(p);
    bf2x2(t.x, dst[0], dst[1]); bf2x2(t.y, dst[2], dst[3]);
  }
}

// ---- gat1 helpers (D=512) ----
__device__ __forceinline__ void g1_load6(
    const u16* __restrict__ XLR, const int* __restrict__ srcs,
    int j, int laneoff, float xs[6][8])
{
#pragma unroll
  for (int q = 0; q < 6; ++q)
    load_row<8>(XLR + (size_t)srcs[j + q] * 1024 + laneoff, xs[q]);
}

__device__ __forceinline__ void g1_compute6(
    const float xs[6][8], const float xr[8],
    const float c1[8], const float c2[8],
    float p0, float& den, float acc[8])
{
  float p[6];
#pragma unroll
  for (int q = 0; q < 6; ++q) {
    float pp = 0.f;
#pragma unroll
    for (int w = 0; w < 8; ++w) {
      float v = xs[q][w] + xr[w];
      pp = fmaf(c1[w], v, fmaf(c2[w], fabsf(v), pp));
    }
    p[q] = pp;
  }
#pragma unroll
  for (int q = 0; q < 6; ++q)
    p[q] += __int_as_float(__builtin_amdgcn_ds_swizzle(__float_as_int(p[q]), 0x041F));
#pragma unroll
  for (int q = 0; q < 6; ++q)
    p[q] += __int_as_float(__builtin_amdgcn_ds_swizzle(__float_as_int(p[q]), 0x081F));
#pragma unroll
  for (int q = 0; q < 6; ++q)
    p[q] += __int_as_float(__builtin_amdgcn_ds_swizzle(__float_as_int(p[q]), 0x101F));
  float e[6];
#pragma unroll
  for (int q = 0; q < 6; ++q) e[q] = __expf(p[q] - p0);
  den += ((e[0] + e[1]) + (e[2] + e[3])) + (e[4] + e[5]);
#pragma unroll
  for (int w = 0; w < 8; ++w) {
    float t0 = fmaf(e[0], xs[0][w], fmaf(e[1], xs[1][w], acc[w]));
    float t1 = fmaf(e[2], xs[2][w], fmaf(e[3], xs[3][w], t0));
    acc[w] = fmaf(e[4], xs[4][w], fmaf(e[5], xs[5][w], t1));
  }
}

__global__ __launch_bounds__(256) void gat_node1_kernel(
    const u16* __restrict__ XLR,
    const int* __restrict__ rowptr, const int* __restrict__ srcs,
    const float* __restrict__ att, const float* __restrict__ bias,
    u16* __restrict__ Hh, int Nn)
{
  constexpr int D = 512;
  constexpr int VPL = 8;
  const int lane = threadIdx.x & 63;
  const int laneoff = lane * VPL;
  const int wv  = (blockIdx.x * 256 + threadIdx.x) >> 6;
  const int nwv = (gridDim.x * 256) >> 6;

  float c1[VPL], c2[VPL], biasR[VPL];
#pragma unroll
  for (int w = 0; w < VPL; ++w) {
    float a = att[laneoff + w];
    c1[w] = 0.6f * a;
    c2[w] = 0.4f * a;
    biasR[w] = bias[laneoff + w];
  }

  for (int d = wv; d < Nn; d += nwv) {
    float xr[VPL];
    load_row<VPL>(XLR + (size_t)d * (2 * D) + D + laneoff, xr);

    const int jb = rowptr[d], je = rowptr[d + 1];

    float acc[VPL];
    load_row<VPL>(XLR + (size_t)srcs[jb] * (2 * D) + laneoff, acc);
    float p0 = 0.f;
#pragma unroll
    for (int w = 0; w < VPL; ++w) {
      float v = acc[w] + xr[w];
      p0 = fmaf(c1[w], v, fmaf(c2[w], fabsf(v), p0));
    }
    p0 += __int_as_float(__builtin_amdgcn_ds_swizzle(__float_as_int(p0), 0x041F));
    p0 += __int_as_float(__builtin_amdgcn_ds_swizzle(__float_as_int(p0), 0x081F));
    p0 += __int_as_float(__builtin_amdgcn_ds_swizzle(__float_as_int(p0), 0x101F));
    float den = 1.f;

    int j = jb + 1;
    // ---- pipelined 6-edge groups: prefetch group k+1 before computing k ----
    if (j + 5 < je) {
      float xs[6][VPL], ys[6][VPL];
      g1_load6(XLR, srcs, j, laneoff, xs);
      j += 6;
      for (;;) {
        bool haveY = (j + 5 < je);
        if (haveY) { g1_load6(XLR, srcs, j, laneoff, ys); j += 6; }
        g1_compute6(xs, xr, c1, c2, p0, den, acc);
        if (!haveY) break;
        bool haveX = (j + 5 < je);
        if (haveX) { g1_load6(XLR, srcs, j, laneoff, xs); j += 6; }
        g1_compute6(ys, xr, c1, c2, p0, den, acc);
        if (!haveX) break;
      }
    }
    // ---- 4-edge remainder ----
    if (j + 3 < je) {
      float xs[4][VPL];
      float p[4];
#pragma unroll
      for (int q = 0; q < 4; ++q)
        load_row<VPL>(XLR + (size_t)srcs[j + q] * (2 * D) + laneoff, xs[q]);
#pragma unroll
      for (int q = 0; q < 4; ++q) {
        float pp = 0.f;
#pragma unroll
        for (int w = 0; w < VPL; ++w) {
          float v = xs[q][w] + xr[w];
          pp = fmaf(c1[w], v, fmaf(c2[w], fabsf(v), pp));
        }
        p[q] = pp;
      }
#pragma unroll
      for (int q = 0; q < 4; ++q)
        p[q] += __int_as_float(__builtin_amdgcn_ds_swizzle(__float_as_int(p[q]), 0x041F));
#pragma unroll
      for (int q = 0; q < 4; ++q)
        p[q] += __int_as_float(__builtin_amdgcn_ds_swizzle(__float_as_int(p[q]), 0x081F));
#pragma unroll
      for (int q = 0; q < 4; ++q)
        p[q] += __int_as_float(__builtin_amdgcn_ds_swizzle(__float_as_int(p[q]), 0x101F));
      float e[4];
#pragma unroll
      for (int q = 0; q < 4; ++q) e[q] = __expf(p[q] - p0);
      den += (e[0] + e[1]) + (e[2] + e[3]);
#pragma unroll
      for (int w = 0; w < VPL; ++w) {
        float t0 = fmaf(e[0], xs[0][w], fmaf(e[1], xs[1][w], acc[w]));
        acc[w] = fmaf(e[2], xs[2][w], fmaf(e[3], xs[3][w], t0));
      }
      j += 4;
    }
    // ---- 2-edge remainder ----
    if (j + 1 < je) {
      float xa[VPL], xb[VPL];
      load_row<VPL>(XLR + (size_t)srcs[j]     * (2 * D) + laneoff, xa);
      load_row<VPL>(XLR + (size_t)srcs[j + 1] * (2 * D) + laneoff, xb);
      float pa = 0.f, pb = 0.f;
#pragma unroll
      for (int w = 0; w < VPL; ++w) {
        float va = xa[w] + xr[w];
        float vb = xb[w] + xr[w];
        pa = fmaf(c1[w], va, fmaf(c2[w], fabsf(va), pa));
        pb = fmaf(c1[w], vb, fmaf(c2[w], fabsf(vb), pb));
      }
      pa += __int_as_float(__builtin_amdgcn_ds_swizzle(__float_as_int(pa), 0x041F));
      pb += __int_as_float(__builtin_amdgcn_ds_swizzle(__float_as_int(pb), 0x041F));
      pa += __int_as_float(__builtin_amdgcn_ds_swizzle(__float_as_int(pa), 0x081F));
      pb += __int_as_float(__builtin_amdgcn_ds_swizzle(__float_as_int(pb), 0x081F));
      pa += __int_as_float(__builtin_amdgcn_ds_swizzle(__float_as_int(pa), 0x101F));
      pb += __int_as_float(__builtin_amdgcn_ds_swizzle(__float_as_int(pb), 0x101F));
      const float ea = __expf(pa - p0);
      const float eb = __expf(pb - p0);
      den += ea + eb;
#pragma unroll
      for (int w = 0; w < VPL; ++w)
        acc[w] = fmaf(ea, xa[w], fmaf(eb, xb[w], acc[w]));
      j += 2;
    }
    // ---- 1-edge remainder ----
    if (j < je) {
      float xa[VPL];
      load_row<VPL>(XLR + (size_t)srcs[j] * (2 * D) + laneoff, xa);
      float pa = 0.f;
#pragma unroll
      for (int w = 0; w < VPL; ++w) {
        float va = xa[w] + xr[w];
        pa = fmaf(c1[w], va, fmaf(c2[w], fabsf(va), pa));
      }
      pa += __int_as_float(__builtin_amdgcn_ds_swizzle(__float_as_int(pa), 0x041F));
      pa += __int_as_float(__builtin_amdgcn_ds_swizzle(__float_as_int(pa), 0x081F));
      pa += __int_as_float(__builtin_amdgcn_ds_swizzle(__float_as_int(pa), 0x101F));
      const float ea = __expf(pa - p0);
      den += ea;
#pragma unroll
      for (int w = 0; w < VPL; ++w) acc[w] = fmaf(ea, xa[w], acc[w]);
    }

    const float inv = 1.f / den;
    float o[VPL];
#pragma unroll
    for (int w = 0; w < VPL; ++w) {
      float v = fmaf(acc[w], inv, biasR[w]);
      o[w] = v > 0.f ? v : (__expf(v) - 1.f);
    }
    uint4 ov = { pk2(o[0], o[1]), pk2(o[2], o[3]), pk2(o[4], o[5]), pk2(o[6], o[7]) };
    *reinterpret_cast<uint4*>(Hh + (size_t)d * D + laneoff) = ov;
  }
}

// ---- gat2 helpers (D=256, half-wave: lanes 0-31 edge j, 32-63 edge j+1) ----
__device__ __forceinline__ void g2_load4(
    const u16* __restrict__ XLR, const int* __restrict__ srcs,
    int j, int half, int l32off, float xs[4][8])
{
#pragma unroll
  for (int q = 0; q < 4; ++q)
    load_row<8>(XLR + (size_t)srcs[j + 2 * q + half] * 512 + l32off, xs[q]);
}

__device__ __forceinline__ void g2_compute4(
    const float xs[4][8], const float xr[8],
    const float c1[8], const float c2[8],
    float p0, float& den, float acc[8])
{
  float p[4];
#pragma unroll
  for (int q = 0; q < 4; ++q) {
    float pp = 0.f;
#pragma unroll
    for (int w = 0; w < 8; ++w) {
      float v = xs[q][w] + xr[w];
      pp = fmaf(c1[w], v, fmaf(c2[w], fabsf(v), pp));
    }
    p[q] = pp;
  }
#pragma unroll
  for (int q = 0; q < 4; ++q)
    p[q] += __int_as_float(__builtin_amdgcn_ds_swizzle(__float_as_int(p[q]), 0x041F));
#pragma unroll
  for (int q = 0; q < 4; ++q)
    p[q] += __int_as_float(__builtin_amdgcn_ds_swizzle(__float_as_int(p[q]), 0x081F));
  float e[4];
#pragma unroll
  for (int q = 0; q < 4; ++q) e[q] = __expf(p[q] - p0);
  den += (e[0] + e[1]) + (e[2] + e[3]);
#pragma unroll
  for (int w = 0; w < 8; ++w) {
    float t0 = fmaf(e[0], xs[0][w], fmaf(e[1], xs[1][w], acc[w]));
    acc[w] = fmaf(e[2], xs[2][w], fmaf(e[3], xs[3][w], t0));
  }
}

__global__ __launch_bounds__(256) void gat_node2_kernel(
    const u16* __restrict__ XLR,
    const int* __restrict__ rowptr, const int* __restrict__ srcs,
    const float* __restrict__ att, const float* __restrict__ bias,
    u16* __restrict__ Hh, int Nn)
{
  constexpr int D = 256;
  const int lane = threadIdx.x & 63;
  const int half = lane >> 5;
  const int l32  = lane & 31;
  const int l32off = l32 * 8;
  const int wv  = (blockIdx.x * 256 + threadIdx.x) >> 6;
  const int nwv = (gridDim.x * 256) >> 6;

  float c1[8], c2[8], biasR[8];
#pragma unroll
  for (int w = 0; w < 8; ++w) {
    float a = att[l32off + w];
    c1[w] = 0.6f * a;
    c2[w] = 0.4f * a;
    biasR[w] = bias[l32off + w];
  }

  for (int d = wv; d < Nn; d += nwv) {
    float xr[8];
    load_row<8>(XLR + (size_t)d * (2 * D) + D + l32off, xr);

    const int jb = rowptr[d], je = rowptr[d + 1];

    // reference edge loaded by BOTH halves (identical p0); only the lower
    // half keeps its contribution (acc, den) to avoid double counting.
    float acc[8];
    load_row<8>(XLR + (size_t)srcs[jb] * (2 * D) + l32off, acc);
    float p0 = 0.f;
#pragma unroll
    for (int w = 0; w < 8; ++w) {
      float v = acc[w] + xr[w];
      p0 = fmaf(c1[w], v, fmaf(c2[w], fabsf(v), p0));
    }
    p0 += __int_as_float(__builtin_amdgcn_ds_swizzle(__float_as_int(p0), 0x041F));
    p0 += __int_as_float(__builtin_amdgcn_ds_swizzle(__float_as_int(p0), 0x081F));
    float den;
    if (half) {
      den = 0.f;
#pragma unroll
      for (int w = 0; w < 8; ++w) acc[w] = 0.f;
    } else {
      den = 1.f;
    }

    int j = jb + 1;
    // ---- pipelined 8-edge groups (4 loads each) ----
    if (j + 7 < je) {
      float xs[4][8], ys[4][8];
      g2_load4(XLR, srcs, j, half, l32off, xs);
      j += 8;
      for (;;) {
        bool haveY = (j + 7 < je);
        if (haveY) { g2_load4(XLR, srcs, j, half, l32off, ys); j += 8; }
        g2_compute4(xs, xr, c1, c2, p0, den, acc);
        if (!haveY) break;
        bool haveX = (j + 7 < je);
        if (haveX) { g2_load4(XLR, srcs, j, half, l32off, xs); j += 8; }
        g2_compute4(ys, xr, c1, c2, p0, den, acc);
        if (!haveX) break;
      }
    }
    // ---- tail: one pair (2 edges) per iteration, masked ----
    for (; j < je; j += 2) {
      int jj = j + half;
      const bool valid = jj < je;
      if (!valid) jj = je - 1;
      float xa[8];
      load_row<8>(XLR + (size_t)srcs[jj] * (2 * D) + l32off, xa);
      float pa = 0.f;
#pragma unroll
      for (int w = 0; w < 8; ++w) {
        float v = xa[w] + xr[w];
        pa = fmaf(c1[w], v, fmaf(c2[w], fabsf(v), pa));
      }
      pa += __int_as_float(__builtin_amdgcn_ds_swizzle(__float_as_int(pa), 0x041F));
      pa += __int_as_float(__builtin_amdgcn_ds_swizzle(__float_as_int(pa), 0x081F));
      const float ea = valid ? __expf(pa - p0) : 0.f;
      den += ea;
#pragma unroll
      for (int w = 0; w < 8; ++w) acc[w] = fmaf(ea, xa[w], acc[w]);
    }

    // ---- merge halves ----
    den += __shfl_xor(den, 32);
#pragma unroll
    for (int w = 0; w < 8; ++w) acc[w] += __shfl_xor(acc[w], 32);

    if (half == 0) {
      const float inv = 1.f / den;
      float o[8];
#pragma unroll
      for (int w = 0; w < 8; ++w) {
        float v = fmaf(acc[w], inv, biasR[w]);
        o[w] = v > 0.f ? v : (__expf(v) - 1.f);
      }
      uint4 ov = { pk2(o[0], o[1]), pk2(o[2], o[3]), pk2(o[4], o[5]), pk2(o[6], o[7]) };
      *reinterpret_cast<uint4*>(Hh + (size_t)d * D + l32off) = ov;
    }
  }
}

// ---------------------------------------------------------------------------

extern "C" void kernel_launch(void* const* d_in, const int* in_sizes, int n_in,
                              void* d_out, int out_size, void* d_ws, size_t ws_size,
                              hipStream_t stream) {
  const float* x     = (const float*)d_in[0];
  const int*   ei    = (const int*)d_in[1];
  const float* Wl1   = (const float*)d_in[2];
  const float* bl1   = (const float*)d_in[3];
  const float* Wr1   = (const float*)d_in[4];
  const float* br1   = (const float*)d_in[5];
  const float* att1  = (const float*)d_in[6];
  const float* bias1 = (const float*)d_in[7];
  const float* Wl2   = (const float*)d_in[8];
  const float* bl2   = (const float*)d_in[9];
  const float* Wr2   = (const float*)d_in[10];
  const float* br2   = (const float*)d_in[11];
  const float* att2  = (const float*)d_in[12];
  const float* bias2 = (const float*)d_in[13];
  const float* Wjk   = (const float*)d_in[14];
  const float* bjk   = (const float*)d_in[15];
  float* out = (float*)d_out;

  const int Nn = in_sizes[0] / 128;   // 20000
  const int E  = in_sizes[1] / 2;     // 320000
  const int ET = E + Nn;              // 340000

  const size_t nx = (size_t)Nn * 128;

  // packed weight region bases (u16 elements)
  const size_t oW1  = 0;
  const size_t oW2  = 262144;
  const size_t oWjk = 786432;
  const size_t npack = 901120;

  // workspace (~85 MB)
  char* ws = (char*)d_ws;
  size_t off = 0;
  u16* XH = (u16*)(ws + off); off += nx * 2;
  u16* Wp = (u16*)(ws + off); off += npack * 2;
  float* BC1 = (float*)(ws + off); off += 1024 * 4;
  float* BC2 = (float*)(ws + off); off += 512 * 4;
  u16* XLR1 = (u16*)(ws + off);               // [N][1024] bf16
  u16* XLR2 = XLR1;                           // [N][512]  (sequential reuse)
  off += (size_t)Nn * 1024 * 2;
  u16* H1h = (u16*)(ws + off); off += (size_t)Nn * 512 * 2;
  u16* H2h = (u16*)(ws + off); off += (size_t)Nn * 256 * 2;
  int* rowptr = (int*)(ws + off); off += (size_t)(Nn + 1) * 4;
  int* cur    = (int*)(ws + off); off += (size_t)Nn * 4;
  int* srcs   = (int*)(ws + off); off += (size_t)ET * 4;

  const int nodeblocks = 5000;   // 20000 waves: 1 node/wave, CP load-balanced

  // ---------------- fused prep+wtrans + CSR build ----------------
  const int nprep = (int)(nx + 1536 + Nn);
  const int prepBlocks = (nprep + 255) / 256;
  prepw_kernel<<<prepBlocks + 124, 256, 0, stream>>>(
      x, bl1, br1, bl2, br2, Wl1, Wr1, Wl2, Wr2, Wjk,
      XH, BC1, BC2, cur, Wp, (int)nx, nprep, prepBlocks);
  hist_kernel<<<(ET + 255) / 256, 256, 0, stream>>>(ei, E, ET, cur);
  scan_kernel<<<1, 1024, 0, stream>>>(cur, rowptr, Nn);   // also re-zeroes cur

  // ---------------- Layer 1 GEMM fused with edge scatter -------------------
  const int g1blocks = (Nn + 31) / 32;
  const int scatBlocks = (ET + 511) / 512;
  gemm1_scatter_kernel<32, 8, 4, true, true, 32 * 136>
      <<<g1blocks + scatBlocks, 512, 0, stream>>>(
      XH, 128, 128,
      Wp + oW1, 4, BC1,
      XLR1, 1024, Nn, 1024, g1blocks,
      ei, E, ET, rowptr, cur, srcs);
  gat_node1_kernel<<<nodeblocks, 256, 0, stream>>>(
      XLR1, rowptr, srcs, att1, bias1, H1h, Nn);

  // ---------------- Layer 2: XLR2 = H1h @ [Wl2|Wr2] (2-term split) ---------
  gemmct_kernel<48, 8, 4, true, true, 48 * 520>
      <<<(Nn + 47) / 48, 512, 0, stream>>>(
      H1h, 512, 512, nullptr, 0, 0, nullptr, 0, 0,
      Wp + oW2, 16, 0, 0, 0, BC2,
      XLR2, 512, Nn, 512);
  gat_node2_kernel<<<nodeblocks, 256, 0, stream>>>(
      XLR2, rowptr, srcs, att2, bias2, H2h, Nn);

  // ---------------- JK: out = [x|h1|h2] @ Wjk + bjk (hi-only, f32 out) -----
  gemmct_kernel<16, 2, 1, false, false, 16 * 920>
      <<<(Nn + 15) / 16, 128, 0, stream>>>(
      XH, 128, 128, H1h, 512, 512, H2h, 256, 256,
      Wp + oWjk, 28, 0, 128, 640, bjk,
      out, 128, Nn, 128);
}

// Round 5
// 298.888 us; speedup vs baseline: 1.0718x; 1.0304x over previous
//
#include <hip/hip_runtime.h>

typedef unsigned short u16;
typedef __attribute__((ext_vector_type(8))) short bf16x8;
typedef __attribute__((ext_vector_type(4))) float f32x4;

__device__ __forceinline__ float bf2f(u16 u) { return __uint_as_float(((unsigned)u) << 16); }
__device__ __forceinline__ u16 f2bf(float f) {
  unsigned u = __float_as_uint(f);
  u += 0x7fffu + ((u >> 16) & 1u);   // RNE
  return (u16)(u >> 16);
}
__device__ __forceinline__ void bf2x2(unsigned w, float& lo, float& hi) {
  lo = __uint_as_float(w << 16);
  hi = __uint_as_float(w & 0xffff0000u);
}
__device__ __forceinline__ unsigned pk2(float lo, float hi) {
  return (unsigned)f2bf(lo) | ((unsigned)f2bf(hi) << 16);
}

// 8-lane aligned-group sum via ds_swizzle (xor 1,2,4 within 32-lane half).
__device__ __forceinline__ float red8(float p) {
  p += __int_as_float(__builtin_amdgcn_ds_swizzle(__float_as_int(p), 0x041F));
  p += __int_as_float(__builtin_amdgcn_ds_swizzle(__float_as_int(p), 0x081F));
  p += __int_as_float(__builtin_amdgcn_ds_swizzle(__float_as_int(p), 0x101F));
  return p;
}
// 4-lane aligned-group sum via ds_swizzle (xor 1,2).
__device__ __forceinline__ float red4(float p) {
  p += __int_as_float(__builtin_amdgcn_ds_swizzle(__float_as_int(p), 0x041F));
  p += __int_as_float(__builtin_amdgcn_ds_swizzle(__float_as_int(p), 0x081F));
  return p;
}

// ---------------------------------------------------------------------------
// Fused prep + weight pack (one dispatch):
// blocks [0, prepBlocks):  x->XH (hi bf16); BC1; BC2; zero cur[Nn].
// blocks [prepBlocks, +124): wtrans: transpose/split/pack weights (r13 layout)
// ---------------------------------------------------------------------------
__global__ __launch_bounds__(256) void prepw_kernel(
    const float* __restrict__ x,
    const float* __restrict__ bl1, const float* __restrict__ br1,
    const float* __restrict__ bl2, const float* __restrict__ br2,
    const float* __restrict__ Wl1, const float* __restrict__ Wr1,
    const float* __restrict__ Wl2, const float* __restrict__ Wr2,
    const float* __restrict__ Wjk,
    u16* __restrict__ XH, float* __restrict__ BC1, float* __restrict__ BC2,
    int* __restrict__ cur, u16* __restrict__ Wp,
    int nx, int total, int prepBlocks)
{
  if (blockIdx.x < prepBlocks) {
    int i = blockIdx.x * 256 + threadIdx.x;
    if (i >= total) return;
    if (i < nx) { XH[i] = f2bf(x[i]); return; }
    int j = i - nx;
    if (j < 1024) { BC1[j] = (j < 512) ? bl1[j] : br1[j - 512]; return; }
    if (j < 1536) { int t = j - 1024; BC2[t] = (t < 256) ? bl2[t] : br2[t - 256]; return; }
    cur[j - 1536] = 0;
    return;
  }
  // ---- wtrans body ----
  __shared__ float T[64][65];
  int t = blockIdx.x - prepBlocks;
  const float *Wa, *Wb; int Nhalf, lds, k0, n0, KsT, SUBS; size_t obase; bool split;
  if (t < 32) {
    int kt = t & 1, nt = t >> 1;
    k0 = kt * 64; n0 = nt * 64; obase = 0; KsT = 4; SUBS = 8; split = true;
    Wa = Wl1; Wb = Wr1; Nhalf = 512; lds = 512;
  } else if (t < 96) {
    int tt = t - 32; int kt = tt & 7, nt = tt >> 3;
    k0 = kt * 64; n0 = nt * 64; obase = 262144; KsT = 16; SUBS = 8; split = true;
    Wa = Wl2; Wb = Wr2; Nhalf = 256; lds = 256;
  } else {
    int tt = t - 96; int kt = tt % 14, nt = tt / 14;
    k0 = kt * 64; n0 = nt * 64; obase = 786432; KsT = 28; SUBS = 4; split = false;
    Wa = Wjk; Wb = nullptr; Nhalf = 128; lds = 128;
  }
  const int tid = threadIdx.x;
  const int lane = tid & 63, unit = tid >> 6;
  {
    int n = n0 + lane;
    const float* S = (n < Nhalf) ? Wa : Wb;
    int nn = (n < Nhalf) ? n : n - Nhalf;
#pragma unroll
    for (int r = 0; r < 16; ++r) {
      int kl = unit + 4 * r;
      T[kl][lane] = S[(size_t)(k0 + kl) * lds + nn];
    }
  }
  __syncthreads();
  const int tn = n0 >> 6;
#pragma unroll
  for (int u = 0; u < 2; ++u) {
    int c = unit * 2 + u;
    int ks_l = c >> 2, nc = c & 3;
    int ksg = (k0 >> 5) + ks_l;
    size_t ob = obase + ((size_t)(tn * KsT + ksg) * SUBS + nc) * 512 + lane * 8;
#pragma unroll
    for (int j = 0; j < 8; ++j) {
      float v = T[ks_l * 32 + (lane >> 4) * 8 + j][nc * 16 + (lane & 15)];
      u16 h = f2bf(v);
      Wp[ob + j] = h;
      if (split) Wp[ob + 2048 + j] = f2bf(v - bf2f(h));
    }
  }
}

// ---------------------------------------------------------------------------
// CSR build: histogram -> exclusive scan (shuffle) -> scatter srcs by dst
// ---------------------------------------------------------------------------
__global__ __launch_bounds__(256) void hist_kernel(
    const int* __restrict__ ei, int E, int ET, int* __restrict__ cnt)
{
  int e = blockIdx.x * 256 + threadIdx.x;
  if (e >= ET) return;
  int d = (e < E) ? ei[E + e] : (e - E);
  atomicAdd(&cnt[d], 1);
}

// scan also re-zeroes cnt (==cur) in place.
__global__ __launch_bounds__(1024) void scan_kernel(
    int* __restrict__ cnt, int* __restrict__ rowptr, int n)
{
  __shared__ int wsum[16];
  __shared__ int carry;
  const int tid = threadIdx.x, lane = tid & 63, wv = tid >> 6;
  if (tid == 0) carry = 0;
  __syncthreads();
  for (int base = 0; base < n; base += 1024) {
    int i = base + tid;
    int v = (i < n) ? cnt[i] : 0;
    if (i < n) cnt[i] = 0;
    int s = v;
#pragma unroll
    for (int ofs = 1; ofs < 64; ofs <<= 1) {
      int t = __shfl_up(s, ofs);
      if (lane >= ofs) s += t;
    }
    if (lane == 63) wsum[wv] = s;
    __syncthreads();
    if (wv == 0 && lane < 16) {
      int t = wsum[lane];
#pragma unroll
      for (int ofs = 1; ofs < 16; ofs <<= 1) {
        int u = __shfl_up(t, ofs);
        if (lane >= ofs) t += u;
      }
      wsum[lane] = t;
    }
    __syncthreads();
    int waveoff = (wv == 0) ? 0 : wsum[wv - 1];
    if (i < n) rowptr[i] = carry + waveoff + s - v;
    int tot = wsum[15];
    __syncthreads();
    if (tid == 0) carry += tot;
    __syncthreads();
  }
  if (threadIdx.x == 0) rowptr[n] = carry;
}

// ---------------------------------------------------------------------------
// GEMM v10 "gemmct" body (operand-swap, packed weights) — device function so
// it can be fused with independent work (scatter) in one dispatch.
// ---------------------------------------------------------------------------
template<int MROWS, int NW, bool SPLIT, bool BF16OUT>
__device__ __forceinline__ void gemmct_body(
    u16* __restrict__ ldsA, int bid,
    const u16* __restrict__ A0, int lda0, int K0,
    const u16* __restrict__ A1, int lda1, int K1,
    const u16* __restrict__ A2, int lda2, int K2,
    const u16* __restrict__ Wp, int KsT,
    int kof0, int kof1, int kof2,
    const float* __restrict__ bias,
    void* __restrict__ Cv, int ldc, int M, int N)
{
  constexpr int SUBS = SPLIT ? 8 : 4;
  const int tid  = threadIdx.x;
  const int lane = tid & 63;
  const int wv   = tid >> 6;
  const int quad = lane >> 4;
  const int r16  = lane & 15;
  const int m0   = bid * MROWS;

  const u16* As[3]   = {A0, A1, A2};
  const int  Ks[3]   = {K0, K1, K2};
  const int  ldas[3] = {lda0, lda1, lda2};
  const int  kofs[3] = {kof0, kof1, kof2};

  int soff[3];
  int so = 0;
#pragma unroll
  for (int s = 0; s < 3; ++s) {
    const int K = Ks[s];
    soff[s] = so;
    if (K == 0) continue;
    const int stride = K + 8;
    const int cpr = K >> 3;
    const int sh  = 32 - __clz(cpr - 1);
    const int tot = MROWS << sh;
    for (int c = tid; c < tot; c += NW * 64) {
      int row = c >> sh, kc = c & ((1 << sh) - 1);
      if (kc < cpr) {
        int sr = m0 + row; if (sr >= M) sr = M - 1;
        uint4 v = *reinterpret_cast<const uint4*>(As[s] + (size_t)sr * ldas[s] + kc * 8);
        *reinterpret_cast<uint4*>(&ldsA[so + row * stride + kc * 8]) = v;
      }
    }
    so += MROWS * stride;
  }
  __syncthreads();

  constexpr int MM = MROWS / 16;
  for (int n0w = wv * 64; n0w < N; n0w += NW * 64) {
    const int t = n0w >> 6;
    f32x4 acc[MM][4];
#pragma unroll
    for (int mm = 0; mm < MM; ++mm)
#pragma unroll
      for (int nc = 0; nc < 4; ++nc) acc[mm][nc] = (f32x4){0.f, 0.f, 0.f, 0.f};

#pragma unroll
    for (int s = 0; s < 3; ++s) {
      const int K = Ks[s];
      if (K == 0) continue;
      const int stride = K + 8;
      const int ksb = kofs[s] >> 5;
      const u16* lbase = &ldsA[soff[s] + r16 * stride + quad * 8];

#pragma unroll 2
      for (int k0 = 0; k0 < K; k0 += 32) {
        const int ks = ksb + (k0 >> 5);
        const u16* ch = Wp + (((size_t)(t * KsT + ks) * SUBS) << 9) + lane * 8;
        bf16x8 af[MM];
#pragma unroll
        for (int mm = 0; mm < MM; ++mm)
          af[mm] = *reinterpret_cast<const bf16x8*>(lbase + mm * 16 * stride + k0);
        bf16x8 whf[4], wlf[4];
#pragma unroll
        for (int nc = 0; nc < 4; ++nc) {
          whf[nc] = *reinterpret_cast<const bf16x8*>(ch + (nc << 9));
          if (SPLIT) wlf[nc] = *reinterpret_cast<const bf16x8*>(ch + ((4 + nc) << 9));
        }
#pragma unroll
        for (int mm = 0; mm < MM; ++mm)
#pragma unroll
          for (int nc = 0; nc < 4; ++nc) {
            acc[mm][nc] = __builtin_amdgcn_mfma_f32_16x16x32_bf16(whf[nc], af[mm], acc[mm][nc], 0, 0, 0);
            if (SPLIT)
              acc[mm][nc] = __builtin_amdgcn_mfma_f32_16x16x32_bf16(wlf[nc], af[mm], acc[mm][nc], 0, 0, 0);
          }
      }
    }

#pragma unroll
    for (int mm = 0; mm < MM; ++mm) {
      const int m = m0 + mm * 16 + r16;
      if (m >= M) continue;
#pragma unroll
      for (int nc = 0; nc < 4; ++nc) {
        const int n = n0w + nc * 16 + quad * 4;
        float b0 = 0.f, b1 = 0.f, b2 = 0.f, b3 = 0.f;
        if (bias) {
          float4 bv = *reinterpret_cast<const float4*>(bias + n);
          b0 = bv.x; b1 = bv.y; b2 = bv.z; b3 = bv.w;
        }
        float v0 = acc[mm][nc][0] + b0;
        float v1 = acc[mm][nc][1] + b1;
        float v2 = acc[mm][nc][2] + b2;
        float v3 = acc[mm][nc][3] + b3;
        if (BF16OUT) {
          ushort4 o = { f2bf(v0), f2bf(v1), f2bf(v2), f2bf(v3) };
          *reinterpret_cast<ushort4*>((u16*)Cv + (size_t)m * ldc + n) = o;
        } else {
          float4 o = { v0, v1, v2, v3 };
          *reinterpret_cast<float4*>((float*)Cv + (size_t)m * ldc + n) = o;
        }
      }
    }
  }
}

template<int MROWS, int NW, int WPE, bool SPLIT, bool BF16OUT, int LDSU16>
__global__ __launch_bounds__(NW * 64, WPE) void gemmct_kernel(
    const u16* __restrict__ A0, int lda0, int K0,
    const u16* __restrict__ A1, int lda1, int K1,
    const u16* __restrict__ A2, int lda2, int K2,
    const u16* __restrict__ Wp, int KsT,
    int kof0, int kof1, int kof2,
    const float* __restrict__ bias,
    void* __restrict__ Cv, int ldc, int M, int N)
{
  __shared__ u16 ldsA[LDSU16];
  gemmct_body<MROWS, NW, SPLIT, BF16OUT>(
      ldsA, blockIdx.x, A0, lda0, K0, A1, lda1, K1, A2, lda2, K2,
      Wp, KsT, kof0, kof1, kof2, bias, Cv, ldc, M, N);
}

// gemm1 + scatter fused: blocks [0,gemmBlocks) run gemm1; the rest scatter
// srcs by dst (both only depend on scan's output / prepw's output).
template<int MROWS, int NW, int WPE, bool SPLIT, bool BF16OUT, int LDSU16>
__global__ __launch_bounds__(NW * 64, WPE) void gemm1_scatter_kernel(
    const u16* __restrict__ A0, int lda0, int K0,
    const u16* __restrict__ Wp, int KsT,
    const float* __restrict__ bias,
    void* __restrict__ Cv, int ldc, int M, int N, int gemmBlocks,
    const int* __restrict__ ei, int E, int ET,
    const int* __restrict__ rowptr, int* __restrict__ cur, int* __restrict__ srcs)
{
  __shared__ u16 ldsA[LDSU16];
  if ((int)blockIdx.x < gemmBlocks) {
    gemmct_body<MROWS, NW, SPLIT, BF16OUT>(
        ldsA, blockIdx.x, A0, lda0, K0, nullptr, 0, 0, nullptr, 0, 0,
        Wp, KsT, 0, 0, 0, bias, Cv, ldc, M, N);
    return;
  }
  int e = ((int)blockIdx.x - gemmBlocks) * (NW * 64) + (int)threadIdx.x;
  if (e >= ET) return;
  int s, d;
  if (e < E) { s = ei[e]; d = ei[E + e]; } else { s = e - E; d = s; }
  int pos = rowptr[d] + atomicAdd(&cur[d], 1);
  srcs[pos] = s;
}

// ---------------------------------------------------------------------------
// Head-partitioned GATv2 aggregation (XCD-local gathers).
// GATv2 softmax is PER-HEAD: head h of a node only needs the 128B (L1) /
// 64B (L2) head-slice of xl. 8 heads == 8 XCDs: block b handles head (b&7);
// round-robin dispatch maps b%8 -> XCD, so each XCD's reusable gather set is
// the per-head xl slice table: 20000 x 128B = 2.56MB (L1) / 1.28MB (L2),
// L2-RESIDENT (4MB/XCD). Gathers become L2 hits instead of L3 fills (the
// 152MB FETCH floor of the node-major layout).
// Wave = 8 groups x 8 lanes (L1) / 16 groups x 4 lanes (L2); one (node,head)
// unit per group; 16B/lane gathers. Same per-head dot + xor-tree reduce as
// the node-major version (identical FP trees).
// XLR row (u16): [xl(0..D-1) | xr(D..2D-1)].
// ---------------------------------------------------------------------------
template<int VPL>
__device__ __forceinline__ void load_row(const u16* p, float* dst) {
  if constexpr (VPL == 8) {
    uint4 t = *reinterpret_cast<const uint4*>(p);
    bf2x2(t.x, dst[0], dst[1]); bf2x2(t.y, dst[2], dst[3]);
    bf2x2(t.z, dst[4], dst[5]); bf2x2(t.w, dst[6], dst[7]);
  } else {
    uint2 t = *reinterpret_cast<const uint2*>(p);
    bf2x2(t.x, dst[0], dst[1]); bf2x2(t.y, dst[2], dst[3]);
  }
}

// Layer 1: D=512, head slice 64 dims = 8 lanes x 8 dims (128B).
__global__ __launch_bounds__(256) void gath1_kernel(
    const u16* __restrict__ XLR,
    const int* __restrict__ rowptr, const int* __restrict__ srcs,
    const float* __restrict__ att, const float* __restrict__ bias,
    u16* __restrict__ Hh, int Nn)
{
  const int tid   = threadIdx.x;
  const int s     = tid & 7;
  const int gib   = tid >> 3;             // group in block [0,32)
  const int head  = blockIdx.x & 7;       // head == XCD (round-robin dispatch)
  const int chunk = blockIdx.x >> 3;
  const int nch   = gridDim.x >> 3;

  const int hoff = head * 64 + s * 8;     // u16 offset of this lane's 8 dims

  float c1[8], c2[8], biasR[8];
#pragma unroll
  for (int w = 0; w < 8; ++w) {
    float a = att[hoff + w];
    c1[w] = 0.6f * a;
    c2[w] = 0.4f * a;
    biasR[w] = bias[hoff + w];
  }

  for (int d = chunk * 32 + gib; d < Nn; d += nch * 32) {
    float xr[8];
    load_row<8>(XLR + (size_t)d * 1024 + 512 + hoff, xr);
    const int jb = rowptr[d], je = rowptr[d + 1];

    // reference edge
    float acc[8];
    load_row<8>(XLR + (size_t)srcs[jb] * 1024 + hoff, acc);
    float p0 = 0.f;
#pragma unroll
    for (int w = 0; w < 8; ++w) {
      float v = acc[w] + xr[w];
      p0 = fmaf(c1[w], v, fmaf(c2[w], fabsf(v), p0));
    }
    p0 = red8(p0);
    float den = 1.f;

    int j = jb + 1;
    for (; j + 1 < je; j += 2) {
      float xa[8], xb[8];
      load_row<8>(XLR + (size_t)srcs[j]     * 1024 + hoff, xa);
      load_row<8>(XLR + (size_t)srcs[j + 1] * 1024 + hoff, xb);
      float pa = 0.f, pb = 0.f;
#pragma unroll
      for (int w = 0; w < 8; ++w) {
        float va = xa[w] + xr[w];
        float vb = xb[w] + xr[w];
        pa = fmaf(c1[w], va, fmaf(c2[w], fabsf(va), pa));
        pb = fmaf(c1[w], vb, fmaf(c2[w], fabsf(vb), pb));
      }
      pa = red8(pa); pb = red8(pb);
      const float ea = __expf(pa - p0);
      const float eb = __expf(pb - p0);
      den += ea + eb;
#pragma unroll
      for (int w = 0; w < 8; ++w)
        acc[w] = fmaf(ea, xa[w], fmaf(eb, xb[w], acc[w]));
    }
    if (j < je) {
      float xa[8];
      load_row<8>(XLR + (size_t)srcs[j] * 1024 + hoff, xa);
      float pa = 0.f;
#pragma unroll
      for (int w = 0; w < 8; ++w) {
        float va = xa[w] + xr[w];
        pa = fmaf(c1[w], va, fmaf(c2[w], fabsf(va), pa));
      }
      pa = red8(pa);
      const float ea = __expf(pa - p0);
      den += ea;
#pragma unroll
      for (int w = 0; w < 8; ++w) acc[w] = fmaf(ea, xa[w], acc[w]);
    }

    const float inv = 1.f / den;
    float o[8];
#pragma unroll
    for (int w = 0; w < 8; ++w) {
      float v = fmaf(acc[w], inv, biasR[w]);
      o[w] = v > 0.f ? v : (__expf(v) - 1.f);
    }
    uint4 ov = { pk2(o[0], o[1]), pk2(o[2], o[3]), pk2(o[4], o[5]), pk2(o[6], o[7]) };
    *reinterpret_cast<uint4*>(Hh + (size_t)d * 512 + hoff) = ov;
  }
}

// Layer 2: D=256, head slice 32 dims = 4 lanes x 8 dims (64B).
__global__ __launch_bounds__(256) void gath2_kernel(
    const u16* __restrict__ XLR,
    const int* __restrict__ rowptr, const int* __restrict__ srcs,
    const float* __restrict__ att, const float* __restrict__ bias,
    u16* __restrict__ Hh, int Nn)
{
  const int tid   = threadIdx.x;
  const int s     = tid & 3;
  const int gib   = tid >> 2;             // group in block [0,64)
  const int head  = blockIdx.x & 7;
  const int chunk = blockIdx.x >> 3;
  const int nch   = gridDim.x >> 3;

  const int hoff = head * 32 + s * 8;

  float c1[8], c2[8], biasR[8];
#pragma unroll
  for (int w = 0; w < 8; ++w) {
    float a = att[hoff + w];
    c1[w] = 0.6f * a;
    c2[w] = 0.4f * a;
    biasR[w] = bias[hoff + w];
  }

  for (int d = chunk * 64 + gib; d < Nn; d += nch * 64) {
    float xr[8];
    load_row<8>(XLR + (size_t)d * 512 + 256 + hoff, xr);
    const int jb = rowptr[d], je = rowptr[d + 1];

    float acc[8];
    load_row<8>(XLR + (size_t)srcs[jb] * 512 + hoff, acc);
    float p0 = 0.f;
#pragma unroll
    for (int w = 0; w < 8; ++w) {
      float v = acc[w] + xr[w];
      p0 = fmaf(c1[w], v, fmaf(c2[w], fabsf(v), p0));
    }
    p0 = red4(p0);
    float den = 1.f;

    int j = jb + 1;
    for (; j + 1 < je; j += 2) {
      float xa[8], xb[8];
      load_row<8>(XLR + (size_t)srcs[j]     * 512 + hoff, xa);
      load_row<8>(XLR + (size_t)srcs[j + 1] * 512 + hoff, xb);
      float pa = 0.f, pb = 0.f;
#pragma unroll
      for (int w = 0; w < 8; ++w) {
        float va = xa[w] + xr[w];
        float vb = xb[w] + xr[w];
        pa = fmaf(c1[w], va, fmaf(c2[w], fabsf(va), pa));
        pb = fmaf(c1[w], vb, fmaf(c2[w], fabsf(vb), pb));
      }
      pa = red4(pa); pb = red4(pb);
      const float ea = __expf(pa - p0);
      const float eb = __expf(pb - p0);
      den += ea + eb;
#pragma unroll
      for (int w = 0; w < 8; ++w)
        acc[w] = fmaf(ea, xa[w], fmaf(eb, xb[w], acc[w]));
    }
    if (j < je) {
      float xa[8];
      load_row<8>(XLR + (size_t)srcs[j] * 512 + hoff, xa);
      float pa = 0.f;
#pragma unroll
      for (int w = 0; w < 8; ++w) {
        float va = xa[w] + xr[w];
        pa = fmaf(c1[w], va, fmaf(c2[w], fabsf(va), pa));
      }
      pa = red4(pa);
      const float ea = __expf(pa - p0);
      den += ea;
#pragma unroll
      for (int w = 0; w < 8; ++w) acc[w] = fmaf(ea, xa[w], acc[w]);
    }

    const float inv = 1.f / den;
    float o[8];
#pragma unroll
    for (int w = 0; w < 8; ++w) {
      float v = fmaf(acc[w], inv, biasR[w]);
      o[w] = v > 0.f ? v : (__expf(v) - 1.f);
    }
    uint4 ov = { pk2(o[0], o[1]), pk2(o[2], o[3]), pk2(o[4], o[5]), pk2(o[6], o[7]) };
    *reinterpret_cast<uint4*>(Hh + (size_t)d * 256 + hoff) = ov;
  }
}

// ---------------------------------------------------------------------------

extern "C" void kernel_launch(void* const* d_in, const int* in_sizes, int n_in,
                              void* d_out, int out_size, void* d_ws, size_t ws_size,
                              hipStream_t stream) {
  const float* x     = (const float*)d_in[0];
  const int*   ei    = (const int*)d_in[1];
  const float* Wl1   = (const float*)d_in[2];
  const float* bl1   = (const float*)d_in[3];
  const float* Wr1   = (const float*)d_in[4];
  const float* br1   = (const float*)d_in[5];
  const float* att1  = (const float*)d_in[6];
  const float* bias1 = (const float*)d_in[7];
  const float* Wl2   = (const float*)d_in[8];
  const float* bl2   = (const float*)d_in[9];
  const float* Wr2   = (const float*)d_in[10];
  const float* br2   = (const float*)d_in[11];
  const float* att2  = (const float*)d_in[12];
  const float* bias2 = (const float*)d_in[13];
  const float* Wjk   = (const float*)d_in[14];
  const float* bjk   = (const float*)d_in[15];
  float* out = (float*)d_out;

  const int Nn = in_sizes[0] / 128;   // 20000
  const int E  = in_sizes[1] / 2;     // 320000
  const int ET = E + Nn;              // 340000

  const size_t nx = (size_t)Nn * 128;

  // packed weight region bases (u16 elements)
  const size_t oW1  = 0;
  const size_t oW2  = 262144;
  const size_t oWjk = 786432;
  const size_t npack = 901120;

  // workspace (~85 MB)
  char* ws = (char*)d_ws;
  size_t off = 0;
  u16* XH = (u16*)(ws + off); off += nx * 2;
  u16* Wp = (u16*)(ws + off); off += npack * 2;
  float* BC1 = (float*)(ws + off); off += 1024 * 4;
  float* BC2 = (float*)(ws + off); off += 512 * 4;
  u16* XLR1 = (u16*)(ws + off);               // [N][1024] bf16
  u16* XLR2 = XLR1;                           // [N][512]  (sequential reuse)
  off += (size_t)Nn * 1024 * 2;
  u16* H1h = (u16*)(ws + off); off += (size_t)Nn * 512 * 2;
  u16* H2h = (u16*)(ws + off); off += (size_t)Nn * 256 * 2;
  int* rowptr = (int*)(ws + off); off += (size_t)(Nn + 1) * 4;
  int* cur    = (int*)(ws + off); off += (size_t)Nn * 4;
  int* srcs   = (int*)(ws + off); off += (size_t)ET * 4;

  // ---------------- fused prep+wtrans + CSR build ----------------
  const int nprep = (int)(nx + 1536 + Nn);
  const int prepBlocks = (nprep + 255) / 256;
  prepw_kernel<<<prepBlocks + 124, 256, 0, stream>>>(
      x, bl1, br1, bl2, br2, Wl1, Wr1, Wl2, Wr2, Wjk,
      XH, BC1, BC2, cur, Wp, (int)nx, nprep, prepBlocks);
  hist_kernel<<<(ET + 255) / 256, 256, 0, stream>>>(ei, E, ET, cur);
  scan_kernel<<<1, 1024, 0, stream>>>(cur, rowptr, Nn);   // also re-zeroes cur

  // ---------------- Layer 1 GEMM fused with edge scatter -------------------
  const int g1blocks = (Nn + 31) / 32;
  const int scatBlocks = (ET + 511) / 512;
  gemm1_scatter_kernel<32, 8, 4, true, true, 32 * 136>
      <<<g1blocks + scatBlocks, 512, 0, stream>>>(
      XH, 128, 128,
      Wp + oW1, 4, BC1,
      XLR1, 1024, Nn, 1024, g1blocks,
      ei, E, ET, rowptr, cur, srcs);
  // head-partitioned: 8 heads x 625 chunks x 32 nodes = 20000 (one pass)
  gath1_kernel<<<5000, 256, 0, stream>>>(
      XLR1, rowptr, srcs, att1, bias1, H1h, Nn);

  // ---------------- Layer 2: XLR2 = H1h @ [Wl2|Wr2] (2-term split) ---------
  gemmct_kernel<48, 8, 4, true, true, 48 * 520>
      <<<(Nn + 47) / 48, 512, 0, stream>>>(
      H1h, 512, 512, nullptr, 0, 0, nullptr, 0, 0,
      Wp + oW2, 16, 0, 0, 0, BC2,
      XLR2, 512, Nn, 512);
  // 8 heads x 313 chunks x 64 nodes = 20032 >= 20000 (one pass)
  gath2_kernel<<<2504, 256, 0, stream>>>(
      XLR2, rowptr, srcs, att2, bias2, H2h, Nn);

  // ---------------- JK: out = [x|h1|h2] @ Wjk + bjk (hi-only, f32 out) -----
  gemmct_kernel<16, 2, 1, false, false, 16 * 920>
      <<<(Nn + 15) / 16, 128, 0, stream>>>(
      XH, 128, 128, H1h, 512, 512, H2h, 256, 256,
      Wp + oWjk, 28, 0, 128, 640, bjk,
      out, 128, Nn, 128);
}